// Round 7
// baseline (526.200 us; speedup 1.0000x reference)
//
#include <hip/hip_runtime.h>
#include <math.h>

#define PRIME_Y 2654435761u

struct LevelParams { float scale; unsigned res; unsigned size; unsigned offset; };
struct EncParams { LevelParams lv[16]; };

typedef __attribute__((ext_vector_type(8))) short short8;
typedef __attribute__((ext_vector_type(4))) float f32x4;

struct alignas(8) F2 { float x, y; };
struct alignas(8) F2x2 { F2 lo, hi; };   // 16B load, 8B-aligned (gfx950 allows)

// fp32 pair -> packed bf16 (RNE), low = a, high = b
__device__ inline unsigned bf2pack(float a, float b) {
  unsigned ua = __float_as_uint(a);
  unsigned ub = __float_as_uint(b);
  ua = (ua + 0x7FFFu + ((ua >> 16) & 1u)) >> 16;
  ub = (ub + 0x7FFFu + ((ub >> 16) & 1u)) & 0xFFFF0000u;
  return ua | ub;
}

// LDS map (bytes):
//   [0,5120)        sW0  bf16 [64 rows][32] row stride 80
//   [5120,7424)     sW1  bf16 [16 rows][64] row stride 144 (rows 8..15 zero)
//   [7424,44288)    per-wave region, 9216 B each: F bf16 [64][32] stride 80,
//                   then overwritten by reluH bf16 [64][64] stride 144
#define SMEM_BYTES 44288

__global__ __launch_bounds__(256) void plane_fwd(
    const F2* __restrict__ xy,
    const F2* __restrict__ table,
    const float* __restrict__ w0g,
    const float* __restrict__ w1g,
    const int* __restrict__ boundp,
    float* __restrict__ out,
    EncParams P)
{
  __shared__ __align__(16) char smem[SMEM_BYTES];
  const int t = threadIdx.x;
  const int L = t & 63;         // lane in wave
  const int w = t >> 6;         // wave in block
  const int r16 = L & 15;
  const int g = L >> 4;

  // ---- stage W0 (bf16, stride 80) ----
  {
    const float4* s = (const float4*)w0g;     // 512 float4 = 2048 floats
    float4 a = s[t * 2], b = s[t * 2 + 1];
    uint4 pk = make_uint4(bf2pack(a.x, a.y), bf2pack(a.z, a.w),
                          bf2pack(b.x, b.y), bf2pack(b.z, b.w));
    *(uint4*)(smem + (t >> 2) * 80 + (t & 3) * 16) = pk;
  }
  // ---- stage W1 (bf16, [16][64] stride 144, rows 8..15 = 0) ----
  {
    int row = t >> 4;
    int col = (t & 15) * 4;
    float c0 = 0.f, c1 = 0.f, c2 = 0.f, c3 = 0.f;
    if (row < 8) {
      float4 wv = *(const float4*)(w1g + row * 64 + col);
      c0 = wv.x; c1 = wv.y; c2 = wv.z; c3 = wv.w;
    }
    *(uint2*)(smem + 5120 + row * 144 + col * 2) =
        make_uint2(bf2pack(c0, c1), bf2pack(c2, c3));
  }

  char* sFH = smem + 7424 + w * 9216;

  // ---- hashgrid encode ----
  const int gid = blockIdx.x * 256 + t;
  const int p = gid >> 2;
  const int c = t & 3;
  F2 pxy = xy[p];

  int braw = boundp[0];
  float bf = (braw > 0x00800000) ? __int_as_float(braw) : (float)braw;
  float inv2b = 0.5f / bf;
  float xn = (pxy.x + bf) * inv2b;
  float yn = (pxy.y + bf) * inv2b;

  float cx  = fminf(fmaxf(xn * 2048.0f - 0.5f, 0.0f), 2047.0f);
  float cyv = fminf(fmaxf(yn * 2048.0f - 0.5f, 0.0f), 2047.0f);
  float cx0 = floorf(cx), cy0 = floorf(cyv);
  float u = cx - cx0, v = cyv - cy0;
  float cx1 = fminf(cx0 + 1.0f, 2047.0f);
  float cy1 = fminf(cy0 + 1.0f, 2047.0f);

  const float cxc = (c & 1) ? cx1 : cx0;
  const float cyc = (c & 2) ? cy1 : cy0;
  const float wc = ((c & 1) ? u : 1.0f - u) * ((c & 2) ? v : 1.0f - v);

  const float K = 1.0f / 2048.0f;
  const float gx = (cxc + 0.5f) * K;
  const float gy = (cyc + 0.5f) * K;

  unsigned fw[16];

  #pragma unroll
  for (int l = 0; l < 16; ++l) {
    const float scale   = P.lv[l].scale;
    const unsigned res  = P.lv[l].res;
    const unsigned size = P.lv[l].size;
    const unsigned off  = P.lv[l].offset;
    const bool hashed = (res * res) > size;  // wave-uniform

    float px = fmaf(gx, scale, 0.5f);
    float pgx = floorf(px);
    float frx = px - pgx;
    unsigned ux = (unsigned)pgx;

    float py = fmaf(gy, scale, 0.5f);
    float pgy = floorf(py);
    float fry = py - pgy;
    unsigned uy = (unsigned)pgy;

    const F2* tabp = table + off;
    F2 t00, t01, t10, t11;

    if (hashed) {
      const unsigned m = size - 1u;   // size == 2^19
      unsigned hy0 = uy * PRIME_Y;
      unsigned hy1 = (uy + 1u) * PRIME_Y;
      unsigned i00 = (ux ^ hy0) & m;
      unsigned i01 = (ux ^ hy1) & m;
      unsigned i10 = ((ux + 1u) ^ hy0) & m;
      unsigned i11 = ((ux + 1u) ^ hy1) & m;
      t00 = tabp[i00];
      t01 = tabp[i01];
      t10 = tabp[i10];
      t11 = tabp[i11];
    } else {
      // Dense: row-major, x-neighbors adjacent in memory.
      // ux,uy <= res-1 (proved from clip math) => i00 <= res^2-1 < size: no mod.
      unsigned i00 = ux + uy * res;
      unsigned i01r = i00 + res;
      unsigned i01 = i01r >= size ? i01r - size : i01r;
      // Merged 16B loads: {i,i+1}. Memory-safe (next level's region follows);
      // value of .hi wrong only when i == size-1 (true successor wraps to 0).
      F2x2 v0 = *(const F2x2*)(tabp + i00);
      F2x2 v1 = *(const F2x2*)(tabp + i01);
      t00 = v0.lo; t10 = v0.hi;
      t01 = v1.lo; t11 = v1.hi;
      if (i00 == size - 1u) t10 = tabp[0];   // rare exact wrap fixup
      if (i01 == size - 1u) t11 = tabp[0];   // (unreachable when i01r wrapped)
    }

    float wx0 = 1.0f - frx, wx1 = frx;
    float wy0 = 1.0f - fry, wy1 = fry;
    float w00 = wx0 * wy0, w01 = wx0 * wy1, w10 = wx1 * wy0, w11 = wx1 * wy1;

    float fx = w00 * t00.x + w01 * t01.x + w10 * t10.x + w11 * t11.x;
    float fy = w00 * t00.y + w01 * t01.y + w10 * t10.y + w11 * t11.y;
    fw[l] = bf2pack(fx, fy);
  }

  // write this lane's feature row (32 bf16 = 64 B) into sF
  *(uint4*)(sFH + L * 80 +  0) = make_uint4(fw[0],  fw[1],  fw[2],  fw[3]);
  *(uint4*)(sFH + L * 80 + 16) = make_uint4(fw[4],  fw[5],  fw[6],  fw[7]);
  *(uint4*)(sFH + L * 80 + 32) = make_uint4(fw[8],  fw[9],  fw[10], fw[11]);
  *(uint4*)(sFH + L * 80 + 48) = make_uint4(fw[12], fw[13], fw[14], fw[15]);

  __syncthreads();

  // ---- layer 1: Ht[j][m] = W0 . F^T ----
  short8 afr[4], bfr[4];
  #pragma unroll
  for (int b = 0; b < 4; ++b)
    bfr[b] = *(const short8*)(sFH + (16 * b + r16) * 80 + g * 16);
  #pragma unroll
  for (int a = 0; a < 4; ++a)
    afr[a] = *(const short8*)(smem + (16 * a + r16) * 80 + g * 16);

  f32x4 acc[4][4];
  #pragma unroll
  for (int a = 0; a < 4; ++a)
    #pragma unroll
    for (int b = 0; b < 4; ++b)
      acc[a][b] = (f32x4){0.f, 0.f, 0.f, 0.f};

  #pragma unroll
  for (int a = 0; a < 4; ++a)
    #pragma unroll
    for (int b = 0; b < 4; ++b)
      acc[a][b] = __builtin_amdgcn_mfma_f32_16x16x32_bf16(
          afr[a], bfr[b], acc[a][b], 0, 0, 0);

  // relu + bf16, write reluH[m][j] (row m, stride 144); j = 16a + 4g + reg
  #pragma unroll
  for (int a = 0; a < 4; ++a)
    #pragma unroll
    for (int b = 0; b < 4; ++b) {
      f32x4 h = acc[a][b];
      float h0 = fmaxf(h.x, 0.f), h1 = fmaxf(h.y, 0.f);
      float h2 = fmaxf(h.z, 0.f), h3 = fmaxf(h.w, 0.f);
      *(uint2*)(sFH + (16 * b + r16) * 144 + a * 32 + g * 8) =
          make_uint2(bf2pack(h0, h1), bf2pack(h2, h3));
    }

  __syncthreads();

  // ---- layer 2: O^T[o][m] = W1 . reluH^T ----
  f32x4 oacc[4];
  #pragma unroll
  for (int b = 0; b < 4; ++b) oacc[b] = (f32x4){0.f, 0.f, 0.f, 0.f};

  #pragma unroll
  for (int ks = 0; ks < 2; ++ks) {
    short8 a2 = *(const short8*)(smem + 5120 + r16 * 144 + ks * 64 + g * 16);
    #pragma unroll
    for (int b = 0; b < 4; ++b) {
      short8 b2 = *(const short8*)(sFH + (16 * b + r16) * 144 + ks * 64 + g * 16);
      oacc[b] = __builtin_amdgcn_mfma_f32_16x16x32_bf16(a2, b2, oacc[b], 0, 0, 0);
    }
  }

  // ---- blend corners (scale by wc of row m, sum over quad) and store ----
  #pragma unroll
  for (int b = 0; b < 4; ++b) {
    float wcm = __shfl(wc, 16 * b + r16, 64);
    float v0 = oacc[b].x * wcm;
    float v1 = oacc[b].y * wcm;
    float v2 = oacc[b].z * wcm;
    float v3 = oacc[b].w * wcm;
    v0 += __shfl_xor(v0, 1, 64); v0 += __shfl_xor(v0, 2, 64);
    v1 += __shfl_xor(v1, 1, 64); v1 += __shfl_xor(v1, 2, 64);
    v2 += __shfl_xor(v2, 1, 64); v2 += __shfl_xor(v2, 2, 64);
    v3 += __shfl_xor(v3, 1, 64); v3 += __shfl_xor(v3, 2, 64);
    if ((L & 3) == 0 && g < 2) {
      int pt = blockIdx.x * 64 + w * 16 + 4 * b + (r16 >> 2);
      *(f32x4*)(out + (size_t)pt * 8 + 4 * g) = (f32x4){v0, v1, v2, v3};
    }
  }
}

extern "C" void kernel_launch(void* const* d_in, const int* in_sizes, int n_in,
                              void* d_out, int out_size, void* d_ws, size_t ws_size,
                              hipStream_t stream) {
  EncParams P;
  double b = exp2(log2(2048.0 / 16.0) / 15.0);
  unsigned off = 0;
  for (int l = 0; l < 16; ++l) {
    double s = 16.0 * pow(b, (double)l) - 1.0;
    int r = (int)ceil(s) + 1;
    unsigned p = (unsigned)(r * r);
    if (p > 524288u) p = 524288u;        // min(HASHMAP_MAX, r*r)
    p = (p + 7u) / 8u * 8u;              // align to 8 entries
    P.lv[l].scale = (float)s;
    P.lv[l].res = (unsigned)r;
    P.lv[l].size = p;
    P.lv[l].offset = off;
    off += p;
  }

  const int N = in_sizes[0] / 2;  // xy is [N,2]
  plane_fwd<<<N / 64, 256, 0, stream>>>(
      (const F2*)d_in[0], (const F2*)d_in[1],
      (const float*)d_in[2], (const float*)d_in[3],
      (const int*)d_in[4], (float*)d_out, P);
}

// Round 8
// 358.107 us; speedup vs baseline: 1.4694x; 1.4694x over previous
//
#include <hip/hip_runtime.h>
#include <math.h>

#define PRIME_Y 2654435761u

struct LevelParams { float scale; unsigned res; unsigned size; unsigned offset; };
struct EncParams { LevelParams lv[16]; };

typedef __attribute__((ext_vector_type(8))) short short8;
typedef __attribute__((ext_vector_type(4))) float f32x4;

struct alignas(8) F2 { float x, y; };

// fp32 pair -> packed bf16 (RNE), low = a, high = b
__device__ inline unsigned bf2pack(float a, float b) {
  unsigned ua = __float_as_uint(a);
  unsigned ub = __float_as_uint(b);
  ua = (ua + 0x7FFFu + ((ua >> 16) & 1u)) >> 16;
  ub = (ub + 0x7FFFu + ((ub >> 16) & 1u)) & 0xFFFF0000u;
  return ua | ub;
}
__device__ inline F2 bf2unpack(unsigned u) {
  F2 r;
  r.x = __uint_as_float(u << 16);
  r.y = __uint_as_float(u & 0xFFFF0000u);
  return r;
}

// table fp32 [n][2] -> packed bf16 [n]
__global__ __launch_bounds__(256) void cvt_table(const F2* __restrict__ in,
                                                 unsigned* __restrict__ outb,
                                                 int n) {
  int i = blockIdx.x * 256 + threadIdx.x;
  if (i < n) {
    F2 v = in[i];
    outb[i] = bf2pack(v.x, v.y);
  }
}

// LDS map (bytes):
//   [0,5120)        sW0  bf16 [64 rows][32] row stride 80
//   [5120,7424)     sW1  bf16 [16 rows][64] row stride 144 (rows 8..15 zero)
//   [7424,44288)    per-wave region, 9216 B each: F bf16 [64][32] stride 80,
//                   then overwritten by reluH bf16 [64][64] stride 144
#define SMEM_BYTES 44288

// TBF=1: gather from packed-bf16 table (4 B/entry, half the TD bytes).
// R7 lesson: the gather pipe is byte-limited (~8 B/lane-slot), merging loads
// into 16B didn't help; shrinking per-entry bytes is the lever.
template <int TBF>
__global__ __launch_bounds__(256) void plane_fwd(
    const F2* __restrict__ xy,
    const F2* __restrict__ table,
    const unsigned* __restrict__ tbf16,
    const float* __restrict__ w0g,
    const float* __restrict__ w1g,
    const int* __restrict__ boundp,
    float* __restrict__ out,
    EncParams P)
{
  __shared__ __align__(16) char smem[SMEM_BYTES];
  const int t = threadIdx.x;
  const int L = t & 63;
  const int w = t >> 6;
  const int r16 = L & 15;
  const int g = L >> 4;

  // ---- stage W0 (bf16, stride 80) ----
  {
    const float4* s = (const float4*)w0g;
    float4 a = s[t * 2], b = s[t * 2 + 1];
    uint4 pk = make_uint4(bf2pack(a.x, a.y), bf2pack(a.z, a.w),
                          bf2pack(b.x, b.y), bf2pack(b.z, b.w));
    *(uint4*)(smem + (t >> 2) * 80 + (t & 3) * 16) = pk;
  }
  // ---- stage W1 (bf16, [16][64] stride 144, rows 8..15 = 0) ----
  {
    int row = t >> 4;
    int col = (t & 15) * 4;
    float c0 = 0.f, c1 = 0.f, c2 = 0.f, c3 = 0.f;
    if (row < 8) {
      float4 wv = *(const float4*)(w1g + row * 64 + col);
      c0 = wv.x; c1 = wv.y; c2 = wv.z; c3 = wv.w;
    }
    *(uint2*)(smem + 5120 + row * 144 + col * 2) =
        make_uint2(bf2pack(c0, c1), bf2pack(c2, c3));
  }

  char* sFH = smem + 7424 + w * 9216;

  // ---- hashgrid encode ----
  const int gid = blockIdx.x * 256 + t;
  const int p = gid >> 2;
  const int c = t & 3;
  F2 pxy = xy[p];

  int braw = boundp[0];
  float bf = (braw > 0x00800000) ? __int_as_float(braw) : (float)braw;
  float inv2b = 0.5f / bf;
  float xn = (pxy.x + bf) * inv2b;
  float yn = (pxy.y + bf) * inv2b;

  float cx  = fminf(fmaxf(xn * 2048.0f - 0.5f, 0.0f), 2047.0f);
  float cyv = fminf(fmaxf(yn * 2048.0f - 0.5f, 0.0f), 2047.0f);
  float cx0 = floorf(cx), cy0 = floorf(cyv);
  float u = cx - cx0, v = cyv - cy0;
  float cx1 = fminf(cx0 + 1.0f, 2047.0f);
  float cy1 = fminf(cy0 + 1.0f, 2047.0f);

  const float cxc = (c & 1) ? cx1 : cx0;
  const float cyc = (c & 2) ? cy1 : cy0;
  const float wc = ((c & 1) ? u : 1.0f - u) * ((c & 2) ? v : 1.0f - v);

  const float K = 1.0f / 2048.0f;
  const float gx = (cxc + 0.5f) * K;
  const float gy = (cyc + 0.5f) * K;

  unsigned fw[16];

  #pragma unroll
  for (int l = 0; l < 16; ++l) {
    const float scale   = P.lv[l].scale;
    const unsigned res  = P.lv[l].res;
    const unsigned size = P.lv[l].size;
    const unsigned off  = P.lv[l].offset;
    const bool hashed = (res * res) > size;  // wave-uniform

    float px = fmaf(gx, scale, 0.5f);
    float pgx = floorf(px);
    float frx = px - pgx;
    unsigned ux = (unsigned)pgx;

    float py = fmaf(gy, scale, 0.5f);
    float pgy = floorf(py);
    float fry = py - pgy;
    unsigned uy = (unsigned)pgy;

    unsigned i00, i01, i10, i11;
    if (hashed) {
      const unsigned m = size - 1u;   // size == 2^19
      unsigned hy0 = uy * PRIME_Y;
      unsigned hy1 = (uy + 1u) * PRIME_Y;
      i00 = (ux ^ hy0) & m;
      i01 = (ux ^ hy1) & m;
      i10 = ((ux + 1u) ^ hy0) & m;
      i11 = ((ux + 1u) ^ hy1) & m;
    } else {
      unsigned b0 = uy * res, b1 = b0 + res;
      unsigned v00 = ux + b0,      v01 = ux + b1;
      unsigned v10 = ux + 1u + b0, v11 = ux + 1u + b1;
      i00 = v00 >= size ? v00 - size : v00;
      i01 = v01 >= size ? v01 - size : v01;
      i10 = v10 >= size ? v10 - size : v10;
      i11 = v11 >= size ? v11 - size : v11;
    }

    F2 t00, t01, t10, t11;
    if (TBF) {
      const unsigned* tb = tbf16 + off;
      t00 = bf2unpack(tb[i00]);
      t01 = bf2unpack(tb[i01]);
      t10 = bf2unpack(tb[i10]);
      t11 = bf2unpack(tb[i11]);
    } else {
      const F2* tabp = table + off;
      t00 = tabp[i00];
      t01 = tabp[i01];
      t10 = tabp[i10];
      t11 = tabp[i11];
    }

    float wx0 = 1.0f - frx, wx1 = frx;
    float wy0 = 1.0f - fry, wy1 = fry;
    float w00 = wx0 * wy0, w01 = wx0 * wy1, w10 = wx1 * wy0, w11 = wx1 * wy1;

    float fx = w00 * t00.x + w01 * t01.x + w10 * t10.x + w11 * t11.x;
    float fy = w00 * t00.y + w01 * t01.y + w10 * t10.y + w11 * t11.y;
    fw[l] = bf2pack(fx, fy);
  }

  *(uint4*)(sFH + L * 80 +  0) = make_uint4(fw[0],  fw[1],  fw[2],  fw[3]);
  *(uint4*)(sFH + L * 80 + 16) = make_uint4(fw[4],  fw[5],  fw[6],  fw[7]);
  *(uint4*)(sFH + L * 80 + 32) = make_uint4(fw[8],  fw[9],  fw[10], fw[11]);
  *(uint4*)(sFH + L * 80 + 48) = make_uint4(fw[12], fw[13], fw[14], fw[15]);

  __syncthreads();

  // ---- layer 1: Ht[j][m] = W0 . F^T ----
  short8 afr[4], bfr[4];
  #pragma unroll
  for (int b = 0; b < 4; ++b)
    bfr[b] = *(const short8*)(sFH + (16 * b + r16) * 80 + g * 16);
  #pragma unroll
  for (int a = 0; a < 4; ++a)
    afr[a] = *(const short8*)(smem + (16 * a + r16) * 80 + g * 16);

  f32x4 acc[4][4];
  #pragma unroll
  for (int a = 0; a < 4; ++a)
    #pragma unroll
    for (int b = 0; b < 4; ++b)
      acc[a][b] = (f32x4){0.f, 0.f, 0.f, 0.f};

  #pragma unroll
  for (int a = 0; a < 4; ++a)
    #pragma unroll
    for (int b = 0; b < 4; ++b)
      acc[a][b] = __builtin_amdgcn_mfma_f32_16x16x32_bf16(
          afr[a], bfr[b], acc[a][b], 0, 0, 0);

  // relu + bf16, write reluH[m][j] (row m, stride 144); j = 16a + 4g + reg
  #pragma unroll
  for (int a = 0; a < 4; ++a)
    #pragma unroll
    for (int b = 0; b < 4; ++b) {
      f32x4 h = acc[a][b];
      float h0 = fmaxf(h.x, 0.f), h1 = fmaxf(h.y, 0.f);
      float h2 = fmaxf(h.z, 0.f), h3 = fmaxf(h.w, 0.f);
      *(uint2*)(sFH + (16 * b + r16) * 144 + a * 32 + g * 8) =
          make_uint2(bf2pack(h0, h1), bf2pack(h2, h3));
    }

  __syncthreads();

  // ---- layer 2: O^T[o][m] = W1 . reluH^T ----
  f32x4 oacc[4];
  #pragma unroll
  for (int b = 0; b < 4; ++b) oacc[b] = (f32x4){0.f, 0.f, 0.f, 0.f};

  #pragma unroll
  for (int ks = 0; ks < 2; ++ks) {
    short8 a2 = *(const short8*)(smem + 5120 + r16 * 144 + ks * 64 + g * 16);
    #pragma unroll
    for (int b = 0; b < 4; ++b) {
      short8 b2 = *(const short8*)(sFH + (16 * b + r16) * 144 + ks * 64 + g * 16);
      oacc[b] = __builtin_amdgcn_mfma_f32_16x16x32_bf16(a2, b2, oacc[b], 0, 0, 0);
    }
  }

  // ---- blend corners and store ----
  #pragma unroll
  for (int b = 0; b < 4; ++b) {
    float wcm = __shfl(wc, 16 * b + r16, 64);
    float v0 = oacc[b].x * wcm;
    float v1 = oacc[b].y * wcm;
    float v2 = oacc[b].z * wcm;
    float v3 = oacc[b].w * wcm;
    v0 += __shfl_xor(v0, 1, 64); v0 += __shfl_xor(v0, 2, 64);
    v1 += __shfl_xor(v1, 1, 64); v1 += __shfl_xor(v1, 2, 64);
    v2 += __shfl_xor(v2, 1, 64); v2 += __shfl_xor(v2, 2, 64);
    v3 += __shfl_xor(v3, 1, 64); v3 += __shfl_xor(v3, 2, 64);
    if ((L & 3) == 0 && g < 2) {
      int pt = blockIdx.x * 64 + w * 16 + 4 * b + (r16 >> 2);
      *(f32x4*)(out + (size_t)pt * 8 + 4 * g) = (f32x4){v0, v1, v2, v3};
    }
  }
}

extern "C" void kernel_launch(void* const* d_in, const int* in_sizes, int n_in,
                              void* d_out, int out_size, void* d_ws, size_t ws_size,
                              hipStream_t stream) {
  EncParams P;
  double b = exp2(log2(2048.0 / 16.0) / 15.0);
  unsigned off = 0;
  for (int l = 0; l < 16; ++l) {
    double s = 16.0 * pow(b, (double)l) - 1.0;
    int r = (int)ceil(s) + 1;
    unsigned p = (unsigned)(r * r);
    if (p > 524288u) p = 524288u;
    p = (p + 7u) / 8u * 8u;
    P.lv[l].scale = (float)s;
    P.lv[l].res = (unsigned)r;
    P.lv[l].size = p;
    P.lv[l].offset = off;
    off += p;
  }
  const int total_params = (int)off;

  const int N = in_sizes[0] / 2;  // xy is [N,2]
  const F2* xy = (const F2*)d_in[0];
  const F2* table = (const F2*)d_in[1];
  const float* w0g = (const float*)d_in[2];
  const float* w1g = (const float*)d_in[3];
  const int* bp = (const int*)d_in[4];
  float* outp = (float*)d_out;

  if (ws_size >= (size_t)total_params * 4) {
    unsigned* tbf = (unsigned*)d_ws;
    cvt_table<<<(total_params + 255) / 256, 256, 0, stream>>>(table, tbf,
                                                             total_params);
    plane_fwd<1><<<N / 64, 256, 0, stream>>>(xy, table, tbf, w0g, w1g, bp,
                                             outp, P);
  } else {
    plane_fwd<0><<<N / 64, 256, 0, stream>>>(xy, table, nullptr, w0g, w1g, bp,
                                             outp, P);
  }
}